// Round 1
// baseline (195.738 us; speedup 1.0000x reference)
//
#include <hip/hip_runtime.h>
#include <stdint.h>

#define BATCH   65536
#define BM      128
#define BK      32
#define NSTEP   16

typedef __bf16 bf16x8 __attribute__((ext_vector_type(8)));
typedef float  f32x16 __attribute__((ext_vector_type(16)));

__device__ __forceinline__ uint32_t f2bf1(float v) {
  uint32_t u = __float_as_uint(v);
  return (u + 0x7FFFu + ((u >> 16) & 1u)) >> 16;   // RNE bf16
}

__device__ __forceinline__ uint32_t cvt_pk_bf16(float lo, float hi) {
  uint32_t r;
  asm volatile("v_cvt_pk_bf16_f32 %0, %1, %2" : "=v"(r) : "v"(lo), "v"(hi));
  return r;
}

__device__ __forceinline__ float fast_sigmoid(float x) {
  return __builtin_amdgcn_rcpf(1.0f + __expf(-x));
}
__device__ __forceinline__ float fast_tanh(float x) {
  // tanh(x) = 1 - 2/(exp(2x)+1); saturates correctly at +/-inf
  return 1.0f - 2.0f * __builtin_amdgcn_rcpf(1.0f + __expf(2.0f * x));
}

// ---------------- prep: weights -> gathered/transposed/swizzled bf16 image ----------------
// 16B chunk index t = ((nb*16 + ks)*128 + n)*4 + slot
// holds Wcat[k = ks*32 + (slot ^ ((n>>1)&3))*8 + i][ (n>>5)*256 + nb*32 + (n&31) ], i=0..7
// where Wcat rows 0..255 = kernel, 256..511 = recurrent_kernel.
__global__ __launch_bounds__(256) void prep_weights(
    const float* __restrict__ wk, const float* __restrict__ wr,
    uint4* __restrict__ wsw) {
  int t    = blockIdx.x * 256 + threadIdx.x;   // 0..65535
  int slot = t & 3;
  int n    = (t >> 2) & 127;
  int ks   = (t >> 9) & 15;
  int nb   = t >> 13;
  int cch  = slot ^ ((n >> 1) & 3);
  int k0   = ks * 32 + cch * 8;
  int col  = (n >> 5) * 256 + nb * 32 + (n & 31);
  uint32_t o[4];
#pragma unroll
  for (int p = 0; p < 4; ++p) {
    int k = k0 + p * 2;
    const float* s0 = (k < 256) ? (wk + (size_t)k * 1024 + col)
                                : (wr + (size_t)(k - 256) * 1024 + col);
    const float* s1 = (k + 1 < 256) ? (wk + (size_t)(k + 1) * 1024 + col)
                                    : (wr + (size_t)(k - 255) * 1024 + col);
    o[p] = f2bf1(*s0) | (f2bf1(*s1) << 16);
  }
  wsw[t] = make_uint4(o[0], o[1], o[2], o[3]);
}

// ---------------- fused LSTM GEMM ----------------
// block: 128 batch rows x (4 gates x 32 units). 4 waves M-stacked, wave = 32x128.
// acc[g] = 32x32 MFMA tile of gate g -> gate math fully in-register.
__global__ __launch_bounds__(256) void lstm_fused(
    const float* __restrict__ xp, const float* __restrict__ hp,
    const float* __restrict__ cp, const float* __restrict__ bp,
    const uint32_t* __restrict__ wsw, float* __restrict__ outp) {

  __shared__ __align__(16) char smem[32768];
  // A: [0,8192) buf0, [8192,16384) buf1 ; B: [16384,24576) buf0, [24576,32768) buf1

  const int tid  = threadIdx.x;
  const int lane = tid & 63;
  const int wv   = tid >> 6;
  const int ln31 = lane & 31;
  const int hi32 = lane >> 5;
  const int rt   = blockIdx.x;   // 512 row tiles
  const int nb   = blockIdx.y;   // 8 unit blocks

  // ---- A staging constants (reg-stage fp32 -> bf16, swizzled ds_write) ----
  const int arow0 = tid >> 3;          // 0..31
  const int ac4   = tid & 7;           // which float4 of the 32-k strip
  const float* xsrc = xp + (size_t)(rt * BM + arow0) * 256 + ac4 * 4;
  const float* hsrc = hp + (size_t)(rt * BM + arow0) * 256 + ac4 * 4;
  const int aswz_w = (arow0 >> 1) & 3;  // j-invariant since rows step by 32
  int awoff[4];
#pragma unroll
  for (int j = 0; j < 4; ++j) {
    int r = arow0 + 32 * j;
    awoff[j] = r * 64 + (((ac4 >> 1) ^ aswz_w) << 4) + ((ac4 & 1) << 3);
  }

  // ---- B staging: wave wv DMA-copies image chunks 2wv, 2wv+1 (1KB each) ----
  const uint32_t* bsrc0 = wsw + (size_t)nb * 16 * 2048 + (2 * wv) * 256 + lane * 4;

  // ---- compute-side LDS read offsets (loop-invariant) ----
  const int amr    = wv * 32 + ln31;           // A row for this wave
  const int aswz_r = (amr >> 1) & 3;
  int aro[2], bro[8];
#pragma unroll
  for (int hh = 0; hh < 2; ++hh) {
    aro[hh] = amr * 64 + (((hh * 2 + hi32) ^ aswz_r) << 4);
#pragma unroll
    for (int g = 0; g < 4; ++g) {
      int n = g * 32 + ln31;
      bro[g * 2 + hh] = n * 64 + (((hh * 2 + hi32) ^ ((n >> 1) & 3)) << 4);
    }
  }

  f32x16 acc[4];
#pragma unroll
  for (int g = 0; g < 4; ++g)
#pragma unroll
    for (int i = 0; i < 16; ++i) acc[g][i] = 0.0f;

  float4 areg[4];

  auto load_a = [&](int ks) {
    const float* s = (ks < 8) ? (xsrc + ks * 32) : (hsrc + (ks - 8) * 32);
#pragma unroll
    for (int j = 0; j < 4; ++j)
      areg[j] = *(const float4*)(s + (size_t)j * 32 * 256);
  };
  auto write_a = [&](int buf) {
    char* base = smem + buf * 8192;
#pragma unroll
    for (int j = 0; j < 4; ++j) {
      uint32_t p0 = cvt_pk_bf16(areg[j].x, areg[j].y);
      uint32_t p1 = cvt_pk_bf16(areg[j].z, areg[j].w);
      *(uint2*)(base + awoff[j]) = make_uint2(p0, p1);
    }
  };
  auto glds_b = [&](int ks, int buf) {
    const uint32_t* src = bsrc0 + (size_t)ks * 2048;
    char* dst = smem + 16384 + buf * 8192 + (2 * wv) * 1024;
    __builtin_amdgcn_global_load_lds(
        (const __attribute__((address_space(1))) uint32_t*)src,
        (__attribute__((address_space(3))) uint32_t*)dst, 16, 0, 0);
    __builtin_amdgcn_global_load_lds(
        (const __attribute__((address_space(1))) uint32_t*)(src + 256),
        (__attribute__((address_space(3))) uint32_t*)(dst + 1024), 16, 0, 0);
  };
  auto compute = [&](int buf) {
    const char* ab = smem + buf * 8192;
    const char* bb = smem + 16384 + buf * 8192;
#pragma unroll
    for (int hh = 0; hh < 2; ++hh) {
      bf16x8 af = *(const bf16x8*)(ab + aro[hh]);
#pragma unroll
      for (int g = 0; g < 4; ++g) {
        bf16x8 bfr = *(const bf16x8*)(bb + bro[g * 2 + hh]);
        acc[g] = __builtin_amdgcn_mfma_f32_32x32x16_bf16(af, bfr, acc[g], 0, 0, 0);
      }
    }
  };

  // prologue: stage K-step 0
  load_a(0);
  write_a(0);
  glds_b(0, 0);
  __syncthreads();

#pragma unroll 2
  for (int ks = 0; ks < NSTEP; ++ks) {
    const int cur = ks & 1;
    if (ks < NSTEP - 1) {
      glds_b(ks + 1, cur ^ 1);   // DMA next B tile (overlaps compute)
      load_a(ks + 1);            // next A tile into regs (overlaps compute)
    }
    compute(cur);
    if (ks < NSTEP - 1) write_a(cur ^ 1);
    __syncthreads();             // one barrier per K-step (drains vm+lgkm)
  }

  // ---- epilogue: gates + cell update, all in-register per lane ----
  const int u = nb * 32 + ln31;
  const float bi  = bp[u];
  const float bf_ = bp[256 + u];
  const float bg  = bp[512 + u];
  const float bo  = bp[768 + u];
  const int rowbase = rt * BM + wv * 32 + 4 * hi32;
  float* outh = outp;
  float* outc = outp + (size_t)BATCH * 256;
#pragma unroll
  for (int r = 0; r < 16; ++r) {
    int row = rowbase + (r & 3) + 8 * (r >> 2);
    size_t idx = (size_t)row * 256 + u;
    float zi = acc[0][r] + bi;
    float zf = acc[1][r] + bf_;
    float zg = acc[2][r] + bg;
    float zo = acc[3][r] + bo;
    float iv = fast_sigmoid(zi);
    float fv = fast_sigmoid(zf);
    float gv = fast_tanh(zg);
    float ov = fast_sigmoid(zo);
    float cv = cp[idx];
    float cn = fv * cv + iv * gv;
    float hn = ov * fast_tanh(cn);
    outh[idx] = hn;
    outc[idx] = cn;
  }
}

extern "C" void kernel_launch(void* const* d_in, const int* in_sizes, int n_in,
                              void* d_out, int out_size, void* d_ws, size_t ws_size,
                              hipStream_t stream) {
  const float* x  = (const float*)d_in[0];
  const float* h  = (const float*)d_in[1];
  const float* c  = (const float*)d_in[2];
  const float* wk = (const float*)d_in[3];
  const float* wr = (const float*)d_in[4];
  const float* b  = (const float*)d_in[5];
  // weights image: 65536 x 16B = 1 MB in d_ws
  prep_weights<<<256, 256, 0, stream>>>(wk, wr, (uint4*)d_ws);
  lstm_fused<<<dim3(512, 8), 256, 0, stream>>>(x, h, c, b,
                                               (const uint32_t*)d_ws,
                                               (float*)d_out);
}